// Round 1
// baseline (721.160 us; speedup 1.0000x reference)
//
#include <hip/hip_runtime.h>

#define D 128

// ---------------- histogram: counts per edge and per vertex ----------------
__global__ void hist_kernel(const int* __restrict__ vertex, const int* __restrict__ edges,
                            int* __restrict__ cntE, int* __restrict__ cntV, int M) {
  int m = blockIdx.x * blockDim.x + threadIdx.x;
  if (m >= M) return;
  atomicAdd(&cntE[edges[m]], 1);
  atomicAdd(&cntV[vertex[m]], 1);
}

// ---------------- exclusive scan (in-place) + cursor copy ------------------
// block 0 scans AE (lenE), block 1 scans AV (lenN). B gets a copy of starts.
__global__ __launch_bounds__(1024) void scan_kernel(int* __restrict__ AE, int* __restrict__ BE, int lenE,
                                                    int* __restrict__ AV, int* __restrict__ BV, int lenN) {
  int* A = (blockIdx.x == 0) ? AE : AV;
  int* B = (blockIdx.x == 0) ? BE : BV;
  int len = (blockIdx.x == 0) ? lenE : lenN;
  int tid = threadIdx.x, lane = tid & 63, w = tid >> 6;
  __shared__ int wsum[16];
  int running = 0;
  int x = (tid < len) ? A[tid] : 0;
  for (int base = 0; base < len; base += 1024) {
    int inext = base + 1024 + tid;
    int xnext = (inext < len) ? A[inext] : 0;  // prefetch next chunk early
    int v = x;
    #pragma unroll
    for (int off = 1; off < 64; off <<= 1) {
      int t = __shfl_up(v, off);
      if (lane >= off) v += t;
    }
    if (lane == 63) wsum[w] = v;
    __syncthreads();
    if (w == 0 && lane < 16) {
      int s = wsum[lane];
      #pragma unroll
      for (int off = 1; off < 16; off <<= 1) {
        int t = __shfl_up(s, off);
        if (lane >= off) s += t;
      }
      wsum[lane] = s;  // inclusive scan of wave totals
    }
    __syncthreads();
    int woff = (w == 0) ? 0 : wsum[w - 1];
    int total = wsum[15];
    int excl = running + woff + v - x;
    int i = base + tid;
    if (i < len) { A[i] = excl; B[i] = excl; }
    running += total;
    __syncthreads();  // protect wsum before next iteration
    x = xnext;
  }
}

// ---------------- scatter: build adjacency lists ---------------------------
__global__ void scatter_kernel(const int* __restrict__ vertex, const int* __restrict__ edges,
                               int* __restrict__ curE, int* __restrict__ curV,
                               int* __restrict__ colE, int* __restrict__ colV, int M) {
  int m = blockIdx.x * blockDim.x + threadIdx.x;
  if (m >= M) return;
  int e = edges[m], v = vertex[m];
  colE[atomicAdd(&curE[e], 1)] = v;
  colV[atomicAdd(&curV[v], 1)] = e;
}

// ---------------- stage 1: vertex->edge mean aggregation -------------------
// one wave per edge; lane holds features [2*lane, 2*lane+1]
__global__ void edge_agg(const float* __restrict__ X, const float* __restrict__ degE,
                         const int* __restrict__ startE, const int* __restrict__ endE,
                         const int* __restrict__ colE, float* __restrict__ Xe, int E) {
  int wid = (blockIdx.x * blockDim.x + threadIdx.x) >> 6;
  int lane = threadIdx.x & 63;
  if (wid >= E) return;
  int start = startE[wid], end = endE[wid];  // endE = cursor after scatter = start+cnt
  const float2* X2 = (const float2*)X;
  float2 acc = {0.f, 0.f};
  for (int idx = start; idx < end; ++idx) {
    int v = colE[idx];
    float2 t = X2[(size_t)v * 64 + lane];
    acc.x += t.x; acc.y += t.y;
  }
  int cnt = end - start;
  float scale = degE[wid] / fmaxf((float)cnt, 1.0f);
  float2 r = {acc.x * scale, acc.y * scale};
  ((float2*)Xe)[(size_t)wid * 64 + lane] = r;
}

// ---------------- stage 2: edge->vertex sum + LN + GCNII + GEMM ------------
// 128 threads per block; thread j owns output feature j; W row j in registers.
__global__ __launch_bounds__(128) void vertex_final(
    const float* __restrict__ Xe, const float* __restrict__ X0,
    const float* __restrict__ degV, const float* __restrict__ W,
    const float* __restrict__ ln_w, const float* __restrict__ ln_b,
    const float* __restrict__ alpha_p, const float* __restrict__ beta_p,
    const int* __restrict__ startV, const int* __restrict__ endV,
    const int* __restrict__ colV, float* __restrict__ out, int N) {
  int j = threadIdx.x;
  int lane = j & 63, wv = j >> 6;

  // preload W row j into registers (static indexing -> stays in VGPRs)
  float w[D];
  const float4* W4 = (const float4*)W;
  #pragma unroll
  for (int k4 = 0; k4 < D / 4; ++k4) {
    float4 t = W4[j * (D / 4) + k4];
    w[4 * k4 + 0] = t.x; w[4 * k4 + 1] = t.y; w[4 * k4 + 2] = t.z; w[4 * k4 + 3] = t.w;
  }
  float lw = ln_w[j], lb = ln_b[j];
  float alpha = *alpha_p, beta = *beta_p;

  __shared__ __align__(16) float xi_s[D];
  __shared__ float red[4];

  for (int n = blockIdx.x; n < N; n += gridDim.x) {
    int start = startV[n], end = endV[n];
    float acc = 0.f;
    for (int idx = start; idx < end; ++idx) {
      int e = colV[idx];
      acc += Xe[(size_t)e * D + j];
    }
    float xh = 2.0f * acc * degV[n];

    // LayerNorm over 128 features (2 waves)
    float s = xh, q = xh * xh;
    #pragma unroll
    for (int off = 1; off < 64; off <<= 1) {
      s += __shfl_xor(s, off);
      q += __shfl_xor(q, off);
    }
    if (lane == 0) { red[wv * 2] = s; red[wv * 2 + 1] = q; }
    __syncthreads();
    float S = red[0] + red[2], Q = red[1] + red[3];
    float mu = S * (1.f / D);
    float var = Q * (1.f / D) - mu * mu;
    float rstd = rsqrtf(var + 1e-5f);
    float xn = (xh - mu) * rstd * lw + lb;
    float xi = (1.f - alpha) * xn + alpha * X0[(size_t)n * D + j];
    xi_s[j] = xi;
    __syncthreads();

    // out[j] = (1-beta)*xi + beta * sum_k xi[k] * W[j][k]
    float dot = 0.f;
    const float4* xs4 = (const float4*)xi_s;
    #pragma unroll
    for (int k4 = 0; k4 < D / 4; ++k4) {
      float4 t = xs4[k4];  // uniform address -> broadcast
      dot = fmaf(t.x, w[4 * k4 + 0], dot);
      dot = fmaf(t.y, w[4 * k4 + 1], dot);
      dot = fmaf(t.z, w[4 * k4 + 2], dot);
      dot = fmaf(t.w, w[4 * k4 + 3], dot);
    }
    out[(size_t)n * D + j] = (1.f - beta) * xi + beta * dot;
    __syncthreads();  // protect xi_s/red before next iteration
  }
}

extern "C" void kernel_launch(void* const* d_in, const int* in_sizes, int n_in,
                              void* d_out, int out_size, void* d_ws, size_t ws_size,
                              hipStream_t stream) {
  const float* X     = (const float*)d_in[0];
  const float* X0    = (const float*)d_in[1];
  const float* degE  = (const float*)d_in[2];
  const float* degV  = (const float*)d_in[3];
  const float* W     = (const float*)d_in[4];
  const float* alpha = (const float*)d_in[5];
  const float* beta  = (const float*)d_in[6];
  const float* lnw   = (const float*)d_in[7];
  const float* lnb   = (const float*)d_in[8];
  const int* vertex  = (const int*)d_in[9];
  const int* edges   = (const int*)d_in[10];

  const int N = in_sizes[0] / D;
  const int E = in_sizes[2];
  const int M = in_sizes[9];

  // workspace layout: [A_E | A_V | B_E | B_V | colE | colV | Xe]
  int* A_E = (int*)d_ws;       // starts (edge), also histogram target
  int* A_V = A_E + E;          // starts (vertex)
  int* B_E = A_V + N;          // cursors (edge); after scatter = segment ends
  int* B_V = B_E + E;          // cursors (vertex)
  int* colE = B_V + N;         // vertices sorted by edge
  int* colV = colE + M;        // edges sorted by vertex
  float* Xe = (float*)(colV + M);  // E x D

  hipMemsetAsync(A_E, 0, (size_t)(E + N) * sizeof(int), stream);
  hist_kernel<<<(M + 255) / 256, 256, 0, stream>>>(vertex, edges, A_E, A_V, M);
  scan_kernel<<<2, 1024, 0, stream>>>(A_E, B_E, E, A_V, B_V, N);
  scatter_kernel<<<(M + 255) / 256, 256, 0, stream>>>(vertex, edges, B_E, B_V, colE, colV, M);
  edge_agg<<<(E + 3) / 4, 256, 0, stream>>>(X, degE, A_E, B_E, colE, Xe, E);
  vertex_final<<<2048, 128, 0, stream>>>(Xe, X0, degV, W, lnw, lnb, alpha, beta,
                                         A_V, B_V, colV, (float*)d_out, N);
}

// Round 2
// 476.424 us; speedup vs baseline: 1.5137x; 1.5137x over previous
//
#include <hip/hip_runtime.h>

#define D 128
#define RPG 8  // vertices per block-iteration in vertex_final

// ---------------- histogram: counts per edge and per vertex ----------------
__global__ void hist_kernel(const int* __restrict__ vertex, const int* __restrict__ edges,
                            int* __restrict__ cntE, int* __restrict__ cntV, int M) {
  int m = blockIdx.x * blockDim.x + threadIdx.x;
  if (m >= M) return;
  atomicAdd(&cntE[edges[m]], 1);
  atomicAdd(&cntV[vertex[m]], 1);
}

// ---------------- hierarchical exclusive scan ------------------------------
__device__ __forceinline__ int block_exscan(int x, int tid, int* wsum) {
  int lane = tid & 63, w = tid >> 6;
  int v = x;
  #pragma unroll
  for (int off = 1; off < 64; off <<= 1) {
    int t = __shfl_up(v, off);
    if (lane >= off) v += t;
  }
  if (lane == 63) wsum[w] = v;
  __syncthreads();
  if (w == 0 && lane < 16) {
    int s = wsum[lane];
    #pragma unroll
    for (int off = 1; off < 16; off <<= 1) {
      int t = __shfl_up(s, off);
      if (lane >= off) s += t;
    }
    wsum[lane] = s;  // inclusive scan of wave totals
  }
  __syncthreads();
  int woff = (w == 0) ? 0 : wsum[w - 1];
  return woff + v - x;  // exclusive prefix within block
}

// phase 1: per-1024-chunk local exclusive scan, block totals -> sums[]
__global__ __launch_bounds__(1024) void scan_local(int* __restrict__ AE, int lenE,
                                                   int* __restrict__ AV, int lenN,
                                                   int* __restrict__ sums, int BE) {
  __shared__ int wsum[16];
  int b = blockIdx.x;
  int* A = (b < BE) ? AE : AV;
  int len = (b < BE) ? lenE : lenN;
  int base = ((b < BE) ? b : (b - BE)) << 10;
  int i = base + threadIdx.x;
  int x = (i < len) ? A[i] : 0;
  int ex = block_exscan(x, threadIdx.x, wsum);
  if (i < len) A[i] = ex;
  if (threadIdx.x == 0) sums[b] = wsum[15];
}

// phase 2: scan the block totals (block 0: edge sums, block 1: vertex sums)
__global__ __launch_bounds__(1024) void scan_sums(int* __restrict__ sums, int BE, int BV) {
  __shared__ int wsum[16];
  int off = (blockIdx.x == 0) ? 0 : BE;
  int len = (blockIdx.x == 0) ? BE : BV;
  int x = (threadIdx.x < len) ? sums[off + threadIdx.x] : 0;
  int ex = block_exscan(x, threadIdx.x, wsum);
  if (threadIdx.x < len) sums[off + threadIdx.x] = ex;
}

// phase 3: add block offsets, write cursor copy
__global__ __launch_bounds__(1024) void scan_add(int* __restrict__ AE, int* __restrict__ BEc, int lenE,
                                                 int* __restrict__ AV, int* __restrict__ BVc, int lenN,
                                                 const int* __restrict__ sums, int BE) {
  int b = blockIdx.x;
  int* A = (b < BE) ? AE : AV;
  int* Bc = (b < BE) ? BEc : BVc;
  int len = (b < BE) ? lenE : lenN;
  int base = ((b < BE) ? b : (b - BE)) << 10;
  int i = base + threadIdx.x;
  if (i < len) {
    int v = A[i] + sums[b];
    A[i] = v;
    Bc[i] = v;
  }
}

// ---------------- scatter: build adjacency lists ---------------------------
__global__ void scatter_kernel(const int* __restrict__ vertex, const int* __restrict__ edges,
                               int* __restrict__ curE, int* __restrict__ curV,
                               int* __restrict__ colE, int* __restrict__ colV, int M) {
  int m = blockIdx.x * blockDim.x + threadIdx.x;
  if (m >= M) return;
  int e = edges[m], v = vertex[m];
  colE[atomicAdd(&curE[e], 1)] = v;
  colV[atomicAdd(&curV[v], 1)] = e;
}

// ---------------- stage 1: vertex->edge mean aggregation -------------------
// one wave per edge; lane holds features [2*lane, 2*lane+1]; 4 loads in flight
__global__ __launch_bounds__(256) void edge_agg(const float* __restrict__ X, const float* __restrict__ degE,
                                                const int* __restrict__ startE, const int* __restrict__ endE,
                                                const int* __restrict__ colE, float* __restrict__ Xe, int E) {
  int wid = (blockIdx.x * blockDim.x + threadIdx.x) >> 6;
  int lane = threadIdx.x & 63;
  if (wid >= E) return;
  int start = startE[wid], end = endE[wid];
  const float2* X2 = (const float2*)X;
  float2 a0 = {0.f, 0.f}, a1 = {0.f, 0.f}, a2 = {0.f, 0.f}, a3 = {0.f, 0.f};
  int idx = start;
  for (; idx + 4 <= end; idx += 4) {
    int e0 = colE[idx], e1 = colE[idx + 1], e2 = colE[idx + 2], e3 = colE[idx + 3];
    float2 t0 = X2[(size_t)e0 * 64 + lane];
    float2 t1 = X2[(size_t)e1 * 64 + lane];
    float2 t2 = X2[(size_t)e2 * 64 + lane];
    float2 t3 = X2[(size_t)e3 * 64 + lane];
    a0.x += t0.x; a0.y += t0.y;
    a1.x += t1.x; a1.y += t1.y;
    a2.x += t2.x; a2.y += t2.y;
    a3.x += t3.x; a3.y += t3.y;
  }
  for (; idx < end; ++idx) {
    float2 t = X2[(size_t)colE[idx] * 64 + lane];
    a0.x += t.x; a0.y += t.y;
  }
  int cnt = end - start;
  float scale = degE[wid] / fmaxf((float)cnt, 1.0f);
  float2 r;
  r.x = ((a0.x + a1.x) + (a2.x + a3.x)) * scale;
  r.y = ((a0.y + a1.y) + (a2.y + a3.y)) * scale;
  ((float2*)Xe)[(size_t)wid * 64 + lane] = r;
}

// ---------------- stage 2: edge->vertex sum + LN + GCNII + GEMM ------------
// 128 threads; thread j owns feature j; W row j held in 32 float4 VGPRs;
// RPG vertices per iteration (independent gather chains, batched LN, 1 sync set)
__global__ __launch_bounds__(128, 2) void vertex_final(
    const float* __restrict__ Xe, const float* __restrict__ X0,
    const float* __restrict__ degV, const float* __restrict__ W,
    const float* __restrict__ ln_w, const float* __restrict__ ln_b,
    const float* __restrict__ alpha_p, const float* __restrict__ beta_p,
    const int* __restrict__ startV, const int* __restrict__ endV,
    const int* __restrict__ colV, float* __restrict__ out, int N) {
  int j = threadIdx.x;
  int lane = j & 63, wv = j >> 6;

  // W row j resident in 128 VGPRs (static indexing only; 256-VGPR cap)
  float4 w[32];
  const float4* W4 = (const float4*)W;
  #pragma unroll
  for (int k = 0; k < 32; ++k) w[k] = W4[j * 32 + k];

  float lw = ln_w[j], lb = ln_b[j];
  float alpha = *alpha_p, beta = *beta_p;

  __shared__ __align__(16) float xi_s[RPG][D];
  __shared__ float red[RPG][4];

  int ngroups = (N + RPG - 1) / RPG;
  for (int g = blockIdx.x; g < ngroups; g += gridDim.x) {
    int n0 = g * RPG;

    // prefetch X0 row elems + degV (independent loads, in flight over gather)
    float x0v[RPG], dv[RPG];
    #pragma unroll
    for (int r = 0; r < RPG; ++r) {
      int n = n0 + r;
      if (n < N) {
        x0v[r] = X0[(size_t)n * D + j];
        dv[r] = degV[n];
      } else {
        x0v[r] = 0.f; dv[r] = 0.f;
      }
    }

    // gather: 4 independent loads in flight per segment
    float acc[RPG];
    #pragma unroll
    for (int r = 0; r < RPG; ++r) {
      acc[r] = 0.f;
      int n = n0 + r;
      if (n < N) {
        int s = startV[n], e = endV[n];
        float p0 = 0.f, p1 = 0.f, p2 = 0.f, p3 = 0.f;
        int idx = s;
        for (; idx + 4 <= e; idx += 4) {
          int e0 = colV[idx], e1 = colV[idx + 1], e2 = colV[idx + 2], e3 = colV[idx + 3];
          p0 += Xe[(size_t)e0 * D + j];
          p1 += Xe[(size_t)e1 * D + j];
          p2 += Xe[(size_t)e2 * D + j];
          p3 += Xe[(size_t)e3 * D + j];
        }
        for (; idx < e; ++idx) p0 += Xe[(size_t)colV[idx] * D + j];
        acc[r] = (p0 + p1) + (p2 + p3);
      }
    }

    // batched LayerNorm reductions (8 rows at once)
    float s8[RPG], q8[RPG];
    #pragma unroll
    for (int r = 0; r < RPG; ++r) {
      float xh = 2.0f * acc[r] * dv[r];
      s8[r] = xh;
      q8[r] = xh * xh;
    }
    #pragma unroll
    for (int off = 1; off < 64; off <<= 1) {
      #pragma unroll
      for (int r = 0; r < RPG; ++r) {
        s8[r] += __shfl_xor(s8[r], off);
        q8[r] += __shfl_xor(q8[r], off);
      }
    }
    if (lane == 0) {
      #pragma unroll
      for (int r = 0; r < RPG; ++r) {
        red[r][wv * 2] = s8[r];
        red[r][wv * 2 + 1] = q8[r];
      }
    }
    __syncthreads();

    float xiv[RPG];
    #pragma unroll
    for (int r = 0; r < RPG; ++r) {
      float S = red[r][0] + red[r][2], Q = red[r][1] + red[r][3];
      float mu = S * (1.f / D);
      float var = Q * (1.f / D) - mu * mu;
      float rstd = rsqrtf(var + 1e-5f);
      float xh = 2.0f * acc[r] * dv[r];
      float xn = (xh - mu) * rstd * lw + lb;
      float xi = (1.f - alpha) * xn + alpha * x0v[r];
      xiv[r] = xi;
      xi_s[r][j] = xi;
    }
    __syncthreads();

    // 8 independent dot chains, W regs reused; xi via uniform LDS broadcast
    #pragma unroll
    for (int r = 0; r < RPG; ++r) {
      int n = n0 + r;
      if (n >= N) break;
      float dot = 0.f;
      const float4* xs4 = (const float4*)xi_s[r];
      #pragma unroll
      for (int k = 0; k < 32; ++k) {
        float4 t = xs4[k];
        dot = fmaf(t.x, w[k].x, dot);
        dot = fmaf(t.y, w[k].y, dot);
        dot = fmaf(t.z, w[k].z, dot);
        dot = fmaf(t.w, w[k].w, dot);
      }
      out[(size_t)n * D + j] = (1.f - beta) * xiv[r] + beta * dot;
    }
    __syncthreads();  // protect xi_s/red before next iteration
  }
}

extern "C" void kernel_launch(void* const* d_in, const int* in_sizes, int n_in,
                              void* d_out, int out_size, void* d_ws, size_t ws_size,
                              hipStream_t stream) {
  const float* X     = (const float*)d_in[0];
  const float* X0    = (const float*)d_in[1];
  const float* degE  = (const float*)d_in[2];
  const float* degV  = (const float*)d_in[3];
  const float* W     = (const float*)d_in[4];
  const float* alpha = (const float*)d_in[5];
  const float* beta  = (const float*)d_in[6];
  const float* lnw   = (const float*)d_in[7];
  const float* lnb   = (const float*)d_in[8];
  const int* vertex  = (const int*)d_in[9];
  const int* edges   = (const int*)d_in[10];

  const int N = in_sizes[0] / D;
  const int E = in_sizes[2];
  const int M = in_sizes[9];

  const int BE = (E + 1023) >> 10;   // scan blocks for edge counts
  const int BV = (N + 1023) >> 10;   // scan blocks for vertex counts

  // workspace layout: [A_E | A_V | B_E | B_V | colE | colV | Xe | sums]
  int* A_E = (int*)d_ws;             // starts (edge); histogram target
  int* A_V = A_E + E;                // starts (vertex)
  int* B_E = A_V + N;                // cursors (edge); after scatter = ends
  int* B_V = B_E + E;                // cursors (vertex)
  int* colE = B_V + N;               // vertices sorted by edge
  int* colV = colE + M;              // edges sorted by vertex
  float* Xe = (float*)(colV + M);    // E x D
  int* sums = (int*)(Xe + (size_t)E * D);  // BE+BV block totals

  hipMemsetAsync(A_E, 0, (size_t)(E + N) * sizeof(int), stream);
  hist_kernel<<<(M + 255) / 256, 256, 0, stream>>>(vertex, edges, A_E, A_V, M);
  scan_local<<<BE + BV, 1024, 0, stream>>>(A_E, E, A_V, N, sums, BE);
  scan_sums<<<2, 1024, 0, stream>>>(sums, BE, BV);
  scan_add<<<BE + BV, 1024, 0, stream>>>(A_E, B_E, E, A_V, B_V, N, sums, BE);
  scatter_kernel<<<(M + 255) / 256, 256, 0, stream>>>(vertex, edges, B_E, B_V, colE, colV, M);
  edge_agg<<<(E + 3) / 4, 256, 0, stream>>>(X, degE, A_E, B_E, colE, Xe, E);
  vertex_final<<<4096, 128, 0, stream>>>(Xe, X0, degV, W, lnw, lnb, alpha, beta,
                                         A_V, B_V, colV, (float*)d_out, N);
}

// Round 3
// 275.317 us; speedup vs baseline: 2.6194x; 1.7305x over previous
//
#include <hip/hip_runtime.h>
#include <hip/hip_fp16.h>
#include <hip/hip_bf16.h>

#define D 128

typedef __attribute__((ext_vector_type(8))) short bf16x8;
typedef __attribute__((ext_vector_type(4))) float f32x4;

// ---------------- histogram ----------------
__global__ void hist_kernel(const int* __restrict__ vertex, const int* __restrict__ edges,
                            int* __restrict__ cntE, int* __restrict__ cntV, int M) {
  int m = blockIdx.x * blockDim.x + threadIdx.x;
  if (m >= M) return;
  atomicAdd(&cntE[edges[m]], 1);
  atomicAdd(&cntV[vertex[m]], 1);
}

// ---------------- hierarchical exclusive scan ------------------------------
__device__ __forceinline__ int block_exscan(int x, int tid, int* wsum) {
  int lane = tid & 63, w = tid >> 6;
  int v = x;
  #pragma unroll
  for (int off = 1; off < 64; off <<= 1) {
    int t = __shfl_up(v, off);
    if (lane >= off) v += t;
  }
  if (lane == 63) wsum[w] = v;
  __syncthreads();
  if (w == 0 && lane < 16) {
    int s = wsum[lane];
    #pragma unroll
    for (int off = 1; off < 16; off <<= 1) {
      int t = __shfl_up(s, off);
      if (lane >= off) s += t;
    }
    wsum[lane] = s;
  }
  __syncthreads();
  int woff = (w == 0) ? 0 : wsum[w - 1];
  return woff + v - x;
}

__global__ __launch_bounds__(1024) void scan_local(int* __restrict__ AE, int lenE,
                                                   int* __restrict__ AV, int lenN,
                                                   int* __restrict__ sums, int BE) {
  __shared__ int wsum[16];
  int b = blockIdx.x;
  int* A = (b < BE) ? AE : AV;
  int len = (b < BE) ? lenE : lenN;
  int base = ((b < BE) ? b : (b - BE)) << 10;
  int i = base + threadIdx.x;
  int x = (i < len) ? A[i] : 0;
  int ex = block_exscan(x, threadIdx.x, wsum);
  if (i < len) A[i] = ex;
  if (threadIdx.x == 0) sums[b] = wsum[15];
}

__global__ __launch_bounds__(1024) void scan_sums(int* __restrict__ sums, int BE, int BV) {
  __shared__ int wsum[16];
  int off = (blockIdx.x == 0) ? 0 : BE;
  int len = (blockIdx.x == 0) ? BE : BV;
  int x = (threadIdx.x < len) ? sums[off + threadIdx.x] : 0;
  int ex = block_exscan(x, threadIdx.x, wsum);
  if (threadIdx.x < len) sums[off + threadIdx.x] = ex;
}

__global__ __launch_bounds__(1024) void scan_add(int* __restrict__ AE, int* __restrict__ BEc, int lenE,
                                                 int* __restrict__ AV, int* __restrict__ BVc, int lenN,
                                                 const int* __restrict__ sums, int BE) {
  int b = blockIdx.x;
  int* A = (b < BE) ? AE : AV;
  int* Bc = (b < BE) ? BEc : BVc;
  int len = (b < BE) ? lenE : lenN;
  int base = ((b < BE) ? b : (b - BE)) << 10;
  int i = base + threadIdx.x;
  if (i < len) {
    int v = A[i] + sums[b];
    A[i] = v;
    Bc[i] = v;
  }
}

// ---------------- scatter ----------------
__global__ void scatter_kernel(const int* __restrict__ vertex, const int* __restrict__ edges,
                               int* __restrict__ curE, int* __restrict__ curV,
                               int* __restrict__ colE, int* __restrict__ colV, int M) {
  int m = blockIdx.x * blockDim.x + threadIdx.x;
  if (m >= M) return;
  int e = edges[m], v = vertex[m];
  colE[atomicAdd(&curE[e], 1)] = v;
  colV[atomicAdd(&curV[v], 1)] = e;
}

// ---------------- fp32 -> fp16 conversion ----------------
__global__ void to_half_kernel(const float* __restrict__ X, __half2* __restrict__ Xh, int n2) {
  int i = blockIdx.x * blockDim.x + threadIdx.x;
  if (i < n2) {
    float2 v = ((const float2*)X)[i];
    Xh[i] = __float22half2_rn(v);
  }
}

// ---------------- stage 1: vertex->edge mean (fp16 gather) ----------------
// one wave per edge; lane holds features {2*lane, 2*lane+1}; 8 loads in flight
__global__ __launch_bounds__(256) void edge_agg_h(
    const __half2* __restrict__ Xh, const float* __restrict__ degE,
    const int* __restrict__ startE, const int* __restrict__ endE,
    const int* __restrict__ colE, __half2* __restrict__ Xe_h, int E) {
  int eid = blockIdx.x * 4 + (threadIdx.x >> 6);
  int lane = threadIdx.x & 63;
  if (eid >= E) return;
  int s = startE[eid], e = endE[eid];
  float ax = 0.f, ay = 0.f;
  for (int idx = s; idx < e; idx += 8) {
    int ii[8];
    #pragma unroll
    for (int t = 0; t < 8; ++t) { int p = idx + t; ii[t] = colE[p < e ? p : s]; }
    #pragma unroll
    for (int t = 0; t < 8; ++t) {
      __half2 h = Xh[(size_t)ii[t] * 64 + lane];
      float2 v = __half22float2(h);
      if (idx + t < e) { ax += v.x; ay += v.y; }
    }
  }
  int cnt = e - s;
  float scale = degE[eid] / fmaxf((float)cnt, 1.0f);
  Xe_h[(size_t)eid * 64 + lane] = __float22half2_rn(make_float2(ax * scale, ay * scale));
}

// ---------------- stage 2: edge->vertex sum + LN + GCNII combine ----------
// one wave per vertex; intra-wave LN (no syncthreads); writes Xi as bf16
__global__ __launch_bounds__(256) void vertex_ln(
    const __half2* __restrict__ Xe_h, const float* __restrict__ X0,
    const float* __restrict__ degV, const float* __restrict__ ln_w,
    const float* __restrict__ ln_b, const float* __restrict__ alpha_p,
    const int* __restrict__ startV, const int* __restrict__ endV,
    const int* __restrict__ colV, __hip_bfloat162* __restrict__ Xi_bf, int N) {
  int n = blockIdx.x * 4 + (threadIdx.x >> 6);
  int lane = threadIdx.x & 63;
  if (n >= N) return;
  int s = startV[n], e = endV[n];
  float ax = 0.f, ay = 0.f;
  for (int idx = s; idx < e; idx += 8) {
    int ii[8];
    #pragma unroll
    for (int t = 0; t < 8; ++t) { int p = idx + t; ii[t] = colV[p < e ? p : s]; }
    #pragma unroll
    for (int t = 0; t < 8; ++t) {
      __half2 h = Xe_h[(size_t)ii[t] * 64 + lane];
      float2 v = __half22float2(h);
      if (idx + t < e) { ax += v.x; ay += v.y; }
    }
  }
  float dv = degV[n];
  float xhx = 2.f * ax * dv, xhy = 2.f * ay * dv;
  float sm = xhx + xhy, q = xhx * xhx + xhy * xhy;
  #pragma unroll
  for (int off = 1; off < 64; off <<= 1) {
    sm += __shfl_xor(sm, off);
    q += __shfl_xor(q, off);
  }
  float mu = sm * (1.f / 128.f);
  float var = q * (1.f / 128.f) - mu * mu;
  float rstd = rsqrtf(var + 1e-5f);
  float2 lw = ((const float2*)ln_w)[lane];
  float2 lb = ((const float2*)ln_b)[lane];
  float2 x0 = ((const float2*)X0)[(size_t)n * 64 + lane];
  float alpha = *alpha_p;
  float xnx = (xhx - mu) * rstd * lw.x + lb.x;
  float xny = (xhy - mu) * rstd * lw.y + lb.y;
  __hip_bfloat162 o;
  o.x = __float2bfloat16((1.f - alpha) * xnx + alpha * x0.x);
  o.y = __float2bfloat16((1.f - alpha) * xny + alpha * x0.y);
  Xi_bf[(size_t)n * 64 + lane] = o;
}

// ---------------- Weff = beta*W^T + (1-beta)*I, bf16, stored [j][k] -------
// Bt[j][k] = Weff[k][j] = beta*W[j][k] + (1-beta)*(j==k)
__global__ void wprep_kernel(const float* __restrict__ W, const float* __restrict__ beta_p,
                             ushort* __restrict__ Wbf) {
  int idx = blockIdx.x * 256 + threadIdx.x;
  int j = idx >> 7, k = idx & 127;
  float beta = *beta_p;
  float v = beta * W[idx] + ((j == k) ? (1.f - beta) : 0.f);
  __hip_bfloat16 b = __float2bfloat16(v);
  Wbf[idx] = *(ushort*)&b;
}

// ---------------- stage 3: out = Xi @ Weff via MFMA bf16 ------------------
// block = 256 thr (4 waves); 128 rows per block; W (32KB) in LDS, XOR-swizzled
__global__ __launch_bounds__(256) void gemm_out(
    const ushort* __restrict__ Xi_bf, const ushort* __restrict__ Wbf,
    float* __restrict__ out, int N) {
  __shared__ __align__(16) ushort Wl[128 * 128];
  // cooperative load W, swizzle 16B chunks: chunk' = chunk ^ (j&7)
  for (int t = threadIdx.x; t < 2048; t += 256) {
    int j = t >> 4, chunk = t & 15;
    bf16x8 v = ((const bf16x8*)Wbf)[t];
    ((bf16x8*)Wl)[j * 16 + (chunk ^ (j & 7))] = v;
  }
  __syncthreads();
  int wv = threadIdx.x >> 6, lane = threadIdx.x & 63;
  int row0 = blockIdx.x * 128 + wv * 32;
  f32x4 acc[2][8] = {};
  #pragma unroll
  for (int ks = 0; ks < 4; ++ks) {
    bf16x8 a[2];
    #pragma unroll
    for (int rt = 0; rt < 2; ++rt) {
      int row = row0 + rt * 16 + (lane & 15);
      row = row < N ? row : N - 1;
      a[rt] = *(const bf16x8*)(Xi_bf + (size_t)row * 128 + ks * 32 + (lane >> 4) * 8);
    }
    int chunk = ks * 4 + (lane >> 4);
    #pragma unroll
    for (int c = 0; c < 8; ++c) {
      int col = c * 16 + (lane & 15);
      bf16x8 b = ((const bf16x8*)Wl)[col * 16 + (chunk ^ (col & 7))];
      acc[0][c] = __builtin_amdgcn_mfma_f32_16x16x32_bf16(a[0], b, acc[0][c], 0, 0, 0);
      acc[1][c] = __builtin_amdgcn_mfma_f32_16x16x32_bf16(a[1], b, acc[1][c], 0, 0, 0);
    }
  }
  #pragma unroll
  for (int rt = 0; rt < 2; ++rt) {
    #pragma unroll
    for (int c = 0; c < 8; ++c) {
      #pragma unroll
      for (int i = 0; i < 4; ++i) {
        int row = row0 + rt * 16 + (lane >> 4) * 4 + i;
        int col = c * 16 + (lane & 15);
        if (row < N) out[(size_t)row * 128 + col] = acc[rt][c][i];
      }
    }
  }
}

extern "C" void kernel_launch(void* const* d_in, const int* in_sizes, int n_in,
                              void* d_out, int out_size, void* d_ws, size_t ws_size,
                              hipStream_t stream) {
  const float* X     = (const float*)d_in[0];
  const float* X0    = (const float*)d_in[1];
  const float* degE  = (const float*)d_in[2];
  const float* degV  = (const float*)d_in[3];
  const float* W     = (const float*)d_in[4];
  const float* alpha = (const float*)d_in[5];
  const float* beta  = (const float*)d_in[6];
  const float* lnw   = (const float*)d_in[7];
  const float* lnb   = (const float*)d_in[8];
  const int* vertex  = (const int*)d_in[9];
  const int* edges   = (const int*)d_in[10];

  const int N = in_sizes[0] / D;
  const int E = in_sizes[2];
  const int M = in_sizes[9];

  const int BE = (E + 1023) >> 10;
  const int BV = (N + 1023) >> 10;

  char* p = (char*)d_ws;
  auto alloc = [&](size_t bytes) { char* r = p; p += (bytes + 255) & ~255ull; return r; };
  int* A_E  = (int*)alloc((size_t)E * 4);
  int* A_V  = (int*)alloc((size_t)N * 4);
  int* B_E  = (int*)alloc((size_t)E * 4);
  int* B_V  = (int*)alloc((size_t)N * 4);
  int* sums = (int*)alloc(1024);
  int* colE = (int*)alloc((size_t)M * 4);
  int* colV = (int*)alloc((size_t)M * 4);
  __half2* X_h  = (__half2*)alloc((size_t)N * D * 2);
  __half2* Xe_h = (__half2*)alloc((size_t)E * D * 2);
  ushort* Wbf   = (ushort*)alloc(16384 * 2);
  // Xi_bf reuses X_h's region (X_h dead after edge_agg_h)
  __hip_bfloat162* Xi_bf = (__hip_bfloat162*)X_h;

  hipMemsetAsync(A_E, 0, (size_t)E * 4, stream);
  hipMemsetAsync(A_V, 0, (size_t)N * 4, stream);
  to_half_kernel<<<(N * 64 + 255) / 256, 256, 0, stream>>>(X, X_h, N * 64);
  hist_kernel<<<(M + 255) / 256, 256, 0, stream>>>(vertex, edges, A_E, A_V, M);
  scan_local<<<BE + BV, 1024, 0, stream>>>(A_E, E, A_V, N, sums, BE);
  scan_sums<<<2, 1024, 0, stream>>>(sums, BE, BV);
  scan_add<<<BE + BV, 1024, 0, stream>>>(A_E, B_E, E, A_V, B_V, N, sums, BE);
  scatter_kernel<<<(M + 255) / 256, 256, 0, stream>>>(vertex, edges, B_E, B_V, colE, colV, M);
  edge_agg_h<<<(E + 3) / 4, 256, 0, stream>>>(X_h, degE, A_E, B_E, colE, Xe_h, E);
  vertex_ln<<<(N + 3) / 4, 256, 0, stream>>>(Xe_h, X0, degV, lnw, lnb, alpha,
                                             A_V, B_V, colV, Xi_bf, N);
  wprep_kernel<<<64, 256, 0, stream>>>(W, beta, Wbf);
  gemm_out<<<(N + 127) / 128, 256, 0, stream>>>((const ushort*)Xi_bf, Wbf, (float*)d_out, N);
}